// Round 1
// baseline (995.187 us; speedup 1.0000x reference)
//
#include <hip/hip_runtime.h>
#include <hip/hip_bf16.h>

// TopKPool: N=8192 nodes, F=256 features, k=4096 kept.
// out = [X_pooled (4096x256 f32) | A_pooled (4096x4096 f32)]
// Key algebraic reduction: A_pooled = A[idx,:] @ A[:,idx]  (0.275 TFLOP)
// instead of (A@A)[idx][:,idx] (1.1 TFLOP). bf16 MFMA, fp32 accumulate.

#define N_NODES 8192
#define F_DIM   256
#define K_SEL   4096

typedef __bf16 bf16x8 __attribute__((ext_vector_type(8)));
typedef float floatx4 __attribute__((ext_vector_type(4)));

__device__ __forceinline__ void async_copy16(const void* g, void* l) {
  __builtin_amdgcn_global_load_lds((const __attribute__((address_space(1))) void*)g,
                                   (__attribute__((address_space(3))) void*)l,
                                   16, 0, 0);
}

// round-to-nearest-even f32 -> bf16 bits (inputs finite)
__device__ __forceinline__ unsigned short f2bf(float x) {
  unsigned u = __float_as_uint(x);
  return (unsigned short)((u + 0x7fffu + ((u >> 16) & 1u)) >> 16);
}

// ---------------- y = X @ (p / ||p||) : one wave per row ----------------
__global__ __launch_bounds__(256) void compute_y(const float* __restrict__ X,
                                                 const float* __restrict__ p,
                                                 float* __restrict__ y) {
  __shared__ __align__(16) float s_p[F_DIM];
  __shared__ float s_part[4];
  __shared__ float s_inv;
  const int tid = threadIdx.x;
  float pv = p[tid];
  s_p[tid] = pv;
  float sq = pv * pv;
  #pragma unroll
  for (int off = 32; off > 0; off >>= 1) sq += __shfl_down(sq, off, 64);
  if ((tid & 63) == 0) s_part[tid >> 6] = sq;
  __syncthreads();
  if (tid == 0) s_inv = rsqrtf(s_part[0] + s_part[1] + s_part[2] + s_part[3]);
  __syncthreads();
  const int wave = tid >> 6, lane = tid & 63;
  const int row = blockIdx.x * 4 + wave;
  const float4* xr = (const float4*)(X + (size_t)row * F_DIM);
  const float4* pr = (const float4*)s_p;
  float4 xv = xr[lane];
  float4 pw = pr[lane];
  float d = xv.x * pw.x + xv.y * pw.y + xv.z * pw.z + xv.w * pw.w;
  #pragma unroll
  for (int off = 32; off > 0; off >>= 1) d += __shfl_down(d, off, 64);
  if (lane == 0) y[row] = d * s_inv;
}

// ---------------- exact top-k (ties -> lower index), idx ascending ----------------
__global__ __launch_bounds__(1024) void topk_select(const float* __restrict__ y,
                                                    int* __restrict__ idx_out) {
  __shared__ unsigned long long k64[N_NODES];   // 64 KB exactly
  unsigned* u32 = (unsigned*)k64;
  const int tid = threadIdx.x;
  for (int i = tid; i < N_NODES; i += 1024) {
    unsigned u = __float_as_uint(y[i]);
    u = (u & 0x80000000u) ? ~u : (u | 0x80000000u);  // order-preserving map
    k64[i] = ((unsigned long long)(~u) << 32) | (unsigned)i;  // asc key = desc value
  }
  __syncthreads();
  for (int k = 2; k <= N_NODES; k <<= 1) {
    for (int j = k >> 1; j > 0; j >>= 1) {
      for (int i = tid; i < N_NODES; i += 1024) {
        int ixj = i ^ j;
        if (ixj > i) {
          bool up = ((i & k) == 0);
          unsigned long long a = k64[i], b = k64[ixj];
          if ((a > b) == up) { k64[i] = b; k64[ixj] = a; }
        }
      }
      __syncthreads();
    }
  }
  unsigned* s = u32 + N_NODES;
  for (int i = tid; i < K_SEL; i += 1024) s[i] = (unsigned)(k64[i] & 0xffffffffu);
  __syncthreads();
  for (int k = 2; k <= K_SEL; k <<= 1) {
    for (int j = k >> 1; j > 0; j >>= 1) {
      for (int i = tid; i < K_SEL; i += 1024) {
        int ixj = i ^ j;
        if (ixj > i) {
          bool up = ((i & k) == 0);
          unsigned a = s[i], b = s[ixj];
          if ((a > b) == up) { s[i] = b; s[ixj] = a; }
        }
      }
      __syncthreads();
    }
  }
  for (int i = tid; i < K_SEL; i += 1024) idx_out[i] = (int)s[i];
}

// ---------------- Abf[m,k] = bf16(A[idx[m],k]) ----------------
__global__ __launch_bounds__(256) void gather_rows(const float* __restrict__ A,
                                                   const int* __restrict__ idx,
                                                   unsigned short* __restrict__ Abf) {
  const int m = blockIdx.x;
  const int src = idx[m];
  const float4* ar = (const float4*)(A + (size_t)src * N_NODES);
  ushort4* orow = (ushort4*)(Abf + (size_t)m * N_NODES);
  for (int i = threadIdx.x; i < N_NODES / 4; i += 256) {
    float4 v = ar[i];
    ushort4 o;
    o.x = f2bf(v.x); o.y = f2bf(v.y); o.z = f2bf(v.z); o.w = f2bf(v.w);
    orow[i] = o;
  }
}

// ---------------- Bt[n,k] = bf16(A[k,idx[n]]) via LDS tile transpose ----------------
__global__ __launch_bounds__(256) void gather_cols(const float* __restrict__ A,
                                                   const int* __restrict__ idx,
                                                   unsigned short* __restrict__ Bt) {
  __shared__ float tile[64][65];
  __shared__ int scol[64];
  const int n0 = blockIdx.x * 64, k0 = blockIdx.y * 64;
  const int tid = threadIdx.x;
  if (tid < 64) scol[tid] = idx[n0 + tid];
  __syncthreads();
  const int tn = tid & 63, tk = tid >> 6;
  #pragma unroll
  for (int kk = 0; kk < 64; kk += 4)
    tile[kk + tk][tn] = A[(size_t)(k0 + kk + tk) * N_NODES + scol[tn]];
  __syncthreads();
  const int tk2 = tid & 63, tn2 = tid >> 6;
  #pragma unroll
  for (int nn = 0; nn < 64; nn += 4)
    Bt[(size_t)(n0 + nn + tn2) * N_NODES + k0 + tk2] = f2bf(tile[tk2][nn + tn2]);
}

// ---------------- X_pooled[r,:] = X[idx[r],:] * tanh(y[idx[r]]) ----------------
__global__ __launch_bounds__(256) void x_pool(const float* __restrict__ X,
                                              const float* __restrict__ y,
                                              const int* __restrict__ idx,
                                              float* __restrict__ out0) {
  const int r = blockIdx.x;
  const int src = idx[r];
  const float g = tanhf(y[src]);
  out0[(size_t)r * F_DIM + threadIdx.x] = X[(size_t)src * F_DIM + threadIdx.x] * g;
}

// ---------------- C[m,n] = sum_k Abf[m,k] * Bt[n,k]  (m97-structure GEMM) ----------------
#define BM 128
#define BN 128
#define BK 32

__global__ __launch_bounds__(256) void gemm_bt(const unsigned short* __restrict__ A,
                                               const unsigned short* __restrict__ B,
                                               float* __restrict__ C) {
  const int Kd = N_NODES;  // 8192
  const int Nd = K_SEL;    // 4096
  __shared__ unsigned short sA[BM * BK];  // 8 KB
  __shared__ unsigned short sB[BN * BK];  // 8 KB
  const int tid = threadIdx.x;
  const int wave = tid >> 6, lane = tid & 63;
  const int m0 = blockIdx.x * BM, n0 = blockIdx.y * BN;
  const int wm = (wave >> 1) * 64, wn = (wave & 1) * 64;

  const int c0 = tid, c1 = tid + 256;
  const unsigned short* Ag0 = A + (size_t)(m0 + (c0 >> 2)) * Kd + (c0 & 3) * 8;
  const unsigned short* Ag1 = A + (size_t)(m0 + (c1 >> 2)) * Kd + (c1 & 3) * 8;
  const unsigned short* Bg0 = B + (size_t)(n0 + (c0 >> 2)) * Kd + (c0 & 3) * 8;
  const unsigned short* Bg1 = B + (size_t)(n0 + (c1 >> 2)) * Kd + (c1 & 3) * 8;
  char* lA0 = (char*)sA + (wave * 64) * 16;
  char* lA1 = (char*)sA + (256 + wave * 64) * 16;
  char* lB0 = (char*)sB + (wave * 64) * 16;
  char* lB1 = (char*)sB + (256 + wave * 64) * 16;

  floatx4 acc[4][4] = {};

  const int a_row = wm + (lane & 15);
  const int b_row = wn + (lane & 15);
  const int k_off = (lane >> 4) * 16;  // bytes

  for (int kt = 0; kt < Kd; kt += BK) {
    async_copy16(Ag0 + kt, lA0);
    async_copy16(Ag1 + kt, lA1);
    async_copy16(Bg0 + kt, lB0);
    async_copy16(Bg1 + kt, lB1);
    __syncthreads();
    bf16x8 av[4], bv[4];
    #pragma unroll
    for (int t = 0; t < 4; ++t) {
      av[t] = *(const bf16x8*)((const char*)sA + (a_row + t * 16) * (BK * 2) + k_off);
      bv[t] = *(const bf16x8*)((const char*)sB + (b_row + t * 16) * (BK * 2) + k_off);
    }
    #pragma unroll
    for (int tm = 0; tm < 4; ++tm)
      #pragma unroll
      for (int tn = 0; tn < 4; ++tn)
        acc[tm][tn] = __builtin_amdgcn_mfma_f32_16x16x32_bf16(av[tm], bv[tn], acc[tm][tn], 0, 0, 0);
    __syncthreads();
  }

  const int cm = (lane >> 4) * 4;
  const int cn = lane & 15;
  #pragma unroll
  for (int tm = 0; tm < 4; ++tm)
    #pragma unroll
    for (int tn = 0; tn < 4; ++tn) {
      float* cp = C + (size_t)(m0 + wm + tm * 16 + cm) * Nd + (n0 + wn + tn * 16 + cn);
      #pragma unroll
      for (int r = 0; r < 4; ++r) cp[(size_t)r * Nd] = acc[tm][tn][r];
    }
}

extern "C" void kernel_launch(void* const* d_in, const int* in_sizes, int n_in,
                              void* d_out, int out_size, void* d_ws, size_t ws_size,
                              hipStream_t stream) {
  const float* X = (const float*)d_in[0];
  const float* A = (const float*)d_in[1];
  const float* p = (const float*)d_in[2];
  float* out0 = (float*)d_out;                      // X_pooled 4096x256
  float* out1 = out0 + (size_t)K_SEL * F_DIM;       // A_pooled 4096x4096

  // ws layout: y (32KB) | idx (16KB) | pad | Abf (64MB) | Bt (64MB) -> 128.06 MB
  char* ws = (char*)d_ws;
  float* y = (float*)ws;
  int* idx = (int*)(ws + 32768);
  unsigned short* Abf = (unsigned short*)(ws + 65536);
  unsigned short* Bt = (unsigned short*)(ws + 65536 + (size_t)K_SEL * N_NODES * 2);

  compute_y<<<N_NODES / 4, 256, 0, stream>>>(X, p, y);
  topk_select<<<1, 1024, 0, stream>>>(y, idx);
  gather_rows<<<K_SEL, 256, 0, stream>>>(A, idx, Abf);
  gather_cols<<<dim3(K_SEL / 64, N_NODES / 64), 256, 0, stream>>>(A, idx, Bt);
  x_pool<<<K_SEL, 256, 0, stream>>>(X, y, idx, out0);
  gemm_bt<<<dim3(K_SEL / BM, K_SEL / BN), 256, 0, stream>>>(Abf, Bt, out1);
}

// Round 2
// 816.981 us; speedup vs baseline: 1.2181x; 1.2181x over previous
//
#include <hip/hip_runtime.h>
#include <hip/hip_bf16.h>

// TopKPool: N=8192 nodes, F=256 features, k=4096 kept.
// out = [X_pooled (4096x256 f32) | A_pooled (4096x4096 f32)]
// A_pooled = A[idx,:] @ A[:,idx] (0.275 TFLOP) instead of (A@A)[idx][:,idx].
// bf16 MFMA, fp32 accumulate. Round 2: radix top-k select, fused single-pass
// gather (one read of A), XOR-swizzled GEMM LDS layout (bank-conflict-free).

#define N_NODES 8192
#define F_DIM   256
#define K_SEL   4096

typedef __bf16 bf16x8 __attribute__((ext_vector_type(8)));
typedef float floatx4 __attribute__((ext_vector_type(4)));

__device__ __forceinline__ void async_copy16(const void* g, void* l) {
  __builtin_amdgcn_global_load_lds((const __attribute__((address_space(1))) void*)g,
                                   (__attribute__((address_space(3))) void*)l,
                                   16, 0, 0);
}

// round-to-nearest-even f32 -> bf16 bits (inputs finite)
__device__ __forceinline__ unsigned short f2bf(float x) {
  unsigned u = __float_as_uint(x);
  return (unsigned short)((u + 0x7fffu + ((u >> 16) & 1u)) >> 16);
}

// ---------------- y = X @ (p / ||p||) : one wave per row ----------------
__global__ __launch_bounds__(256) void compute_y(const float* __restrict__ X,
                                                 const float* __restrict__ p,
                                                 float* __restrict__ y) {
  __shared__ __align__(16) float s_p[F_DIM];
  __shared__ float s_part[4];
  __shared__ float s_inv;
  const int tid = threadIdx.x;
  float pv = p[tid];
  s_p[tid] = pv;
  float sq = pv * pv;
  #pragma unroll
  for (int off = 32; off > 0; off >>= 1) sq += __shfl_down(sq, off, 64);
  if ((tid & 63) == 0) s_part[tid >> 6] = sq;
  __syncthreads();
  if (tid == 0) s_inv = rsqrtf(s_part[0] + s_part[1] + s_part[2] + s_part[3]);
  __syncthreads();
  const int wave = tid >> 6, lane = tid & 63;
  const int row = blockIdx.x * 4 + wave;
  const float4* xr = (const float4*)(X + (size_t)row * F_DIM);
  const float4* pr = (const float4*)s_p;
  float4 xv = xr[lane];
  float4 pw = pr[lane];
  float d = xv.x * pw.x + xv.y * pw.y + xv.z * pw.z + xv.w * pw.w;
  #pragma unroll
  for (int off = 32; off > 0; off >>= 1) d += __shfl_down(d, off, 64);
  if (lane == 0) y[row] = d * s_inv;
}

// ---------------- exact top-k via binary-search select ----------------
// Writes rank[i] = position (0..k-1) among kept nodes in ascending-index
// order, or -1. Ties at the threshold value keep lowest indices (matches
// jax.lax.top_k stability + ascending sort).
__device__ __forceinline__ unsigned block_exscan(unsigned tv, unsigned* scan, int tid) {
  scan[tid] = tv;
  __syncthreads();
  for (int o = 1; o < 1024; o <<= 1) {
    unsigned add = (tid >= o) ? scan[tid - o] : 0u;
    __syncthreads();
    scan[tid] += add;
    __syncthreads();
  }
  unsigned incl = scan[tid];
  __syncthreads();  // allow scan[] reuse
  return incl - tv;
}

__global__ __launch_bounds__(1024) void topk_radix(const float* __restrict__ y,
                                                   int* __restrict__ rank) {
  __shared__ unsigned keys[N_NODES];   // 32 KB
  __shared__ unsigned scan[1024];      // 4 KB
  __shared__ unsigned s_cnt;
  const int tid = threadIdx.x;
  for (int i = tid; i < N_NODES; i += 1024) {
    unsigned u = __float_as_uint(y[i]);
    keys[i] = (u & 0x80000000u) ? ~u : (u | 0x80000000u);  // monotone map
  }
  __syncthreads();
  const int base = tid << 3;
  // T = k-th largest key: largest v with count(keys >= v) >= k
  unsigned lo = 0u, hi = 0xFFFFFFFFu;
  while (lo < hi) {
    unsigned mid = lo + ((hi - lo) >> 1) + 1u;
    if (tid == 0) s_cnt = 0;
    __syncthreads();
    unsigned c = 0;
    #pragma unroll
    for (int j = 0; j < 8; ++j) c += (keys[base + j] >= mid) ? 1u : 0u;
    #pragma unroll
    for (int o = 32; o > 0; o >>= 1) c += __shfl_down(c, o, 64);
    if ((tid & 63) == 0) atomicAdd(&s_cnt, c);
    __syncthreads();
    unsigned tot = s_cnt;
    if (tot >= K_SEL) lo = mid; else hi = mid - 1u;
    __syncthreads();
  }
  const unsigned T = lo;
  // count strictly-greater
  if (tid == 0) s_cnt = 0;
  __syncthreads();
  {
    unsigned c = 0;
    #pragma unroll
    for (int j = 0; j < 8; ++j) c += (keys[base + j] > T) ? 1u : 0u;
    #pragma unroll
    for (int o = 32; o > 0; o >>= 1) c += __shfl_down(c, o, 64);
    if ((tid & 63) == 0) atomicAdd(&s_cnt, c);
  }
  __syncthreads();
  const unsigned need_eq = (unsigned)K_SEL - s_cnt;
  __syncthreads();
  // stable compaction
  unsigned e[8], g[8], te = 0;
  #pragma unroll
  for (int j = 0; j < 8; ++j) {
    unsigned k = keys[base + j];
    e[j] = (k == T) ? 1u : 0u;
    g[j] = (k > T) ? 1u : 0u;
    te += e[j];
  }
  unsigned eqr = block_exscan(te, scan, tid);
  unsigned keep[8], tk = 0;
  #pragma unroll
  for (int j = 0; j < 8; ++j) {
    unsigned kp = g[j] | (e[j] & ((eqr < need_eq) ? 1u : 0u));
    eqr += e[j];
    keep[j] = kp;
    tk += kp;
  }
  unsigned pos = block_exscan(tk, scan, tid);
  #pragma unroll
  for (int j = 0; j < 8; ++j) {
    if (keep[j]) { rank[base + j] = (int)pos; pos++; }
    else rank[base + j] = -1;
  }
}

// ---------------- fused gather: one pass over A ----------------
// Abf[rank[r], c] = bf16(A[r, c])  (selected rows, row-major, K contiguous)
// Bt [rank[c], r] = bf16(A[r, c])  (selected cols, transposed, K contiguous)
__global__ __launch_bounds__(256) void gather_both(const float* __restrict__ A,
                                                   const int* __restrict__ rank,
                                                   unsigned short* __restrict__ Abf,
                                                   unsigned short* __restrict__ Bt) {
  __shared__ float tile[64][65];
  __shared__ int rr_[64], rc_[64];
  const int tid = threadIdx.x;
  const int r0 = blockIdx.y << 6, c0 = blockIdx.x << 6;
  if (tid < 64) rr_[tid] = rank[r0 + tid];
  else if (tid < 128) rc_[tid - 64] = rank[c0 + tid - 64];
  const int trow = tid >> 4, tc4 = (tid & 15) << 2;
  #pragma unroll
  for (int i = 0; i < 4; ++i) {
    const float4 v = *(const float4*)(A + (size_t)(r0 + trow + i * 16) * N_NODES + c0 + tc4);
    tile[trow + i * 16][tc4 + 0] = v.x;
    tile[trow + i * 16][tc4 + 1] = v.y;
    tile[trow + i * 16][tc4 + 2] = v.z;
    tile[trow + i * 16][tc4 + 3] = v.w;
  }
  __syncthreads();
  const int wv = tid >> 6, ln = tid & 63;
  #pragma unroll
  for (int t = 0; t < 16; ++t) {
    int rr = (wv << 4) + t;
    int rk = rr_[rr];                       // wave-uniform branch
    if (rk >= 0) Abf[(size_t)rk * N_NODES + c0 + ln] = f2bf(tile[rr][ln]);
  }
  #pragma unroll
  for (int t = 0; t < 16; ++t) {
    int cc = (wv << 4) + t;
    int rk = rc_[cc];
    if (rk >= 0) Bt[(size_t)rk * N_NODES + r0 + ln] = f2bf(tile[ln][cc]);
  }
}

// ---------------- X_pooled[rank[i],:] = X[i,:] * tanh(y[i]) ----------------
__global__ __launch_bounds__(256) void x_pool(const float* __restrict__ X,
                                              const float* __restrict__ y,
                                              const int* __restrict__ rank,
                                              float* __restrict__ out0) {
  const int i = blockIdx.x;
  const int r = rank[i];
  if (r < 0) return;
  const float g = tanhf(y[i]);
  out0[(size_t)r * F_DIM + threadIdx.x] = X[(size_t)i * F_DIM + threadIdx.x] * g;
}

// ---------------- C[m,n] = sum_k Abf[m,k] * Bt[n,k] ----------------
// m97-structure, with XOR chunk-swizzled LDS: row r's 16B chunk kc lives at
// LDS slot q = (kc + ((r>>1)&3)) & 3. Staging permutes within each 64B row
// segment (coalescing preserved); ds_read_b128 lands 2 lanes/bank-group (free).
#define BM 128
#define BN 128
#define BK 32

__global__ __launch_bounds__(256) void gemm_bt(const unsigned short* __restrict__ A,
                                               const unsigned short* __restrict__ B,
                                               float* __restrict__ C) {
  const int Kd = N_NODES;  // 8192
  const int Nd = K_SEL;    // 4096
  __shared__ unsigned short sA[BM * BK];  // 8 KB
  __shared__ unsigned short sB[BN * BK];  // 8 KB
  const int tid = threadIdx.x;
  const int wave = tid >> 6, lane = tid & 63;
  const int m0 = blockIdx.x * BM, n0 = blockIdx.y * BN;
  const int wm = (wave >> 1) * 64, wn = (wave & 1) * 64;

  // staging: slot s (16B units): row r = s>>2, lds-chunk q = s&3,
  // source global chunk kc = (q - ((r>>1)&3)) & 3
  const int s0 = tid, s1 = tid + 256;
  const int r0s = s0 >> 2, r1s = s1 >> 2;
  const int kc0 = ((s0 & 3) - ((r0s >> 1) & 3)) & 3;
  const int kc1 = ((s1 & 3) - ((r1s >> 1) & 3)) & 3;
  const unsigned short* Ag0 = A + (size_t)(m0 + r0s) * Kd + kc0 * 8;
  const unsigned short* Ag1 = A + (size_t)(m0 + r1s) * Kd + kc1 * 8;
  const unsigned short* Bg0 = B + (size_t)(n0 + r0s) * Kd + kc0 * 8;
  const unsigned short* Bg1 = B + (size_t)(n0 + r1s) * Kd + kc1 * 8;
  char* lA0 = (char*)sA + wave * 1024;
  char* lA1 = (char*)sA + 4096 + wave * 1024;
  char* lB0 = (char*)sB + wave * 1024;
  char* lB1 = (char*)sB + 4096 + wave * 1024;

  floatx4 acc[4][4] = {};

  // read addresses: row R = wm + l15 + 16t, chunk c = lane>>4,
  // lds addr = R*64 + ((c + ((l15>>1)&3))&3)*16   (note (R>>1)&3 == (l15>>1)&3)
  const int l15 = lane & 15;
  const int qa = ((lane >> 4) + ((l15 >> 1) & 3)) & 3;
  const char* sAr = (const char*)sA + (wm + l15) * 64 + qa * 16;
  const char* sBr = (const char*)sB + (wn + l15) * 64 + qa * 16;

  for (int kt = 0; kt < Kd; kt += BK) {
    async_copy16(Ag0 + kt, lA0);
    async_copy16(Ag1 + kt, lA1);
    async_copy16(Bg0 + kt, lB0);
    async_copy16(Bg1 + kt, lB1);
    __syncthreads();
    bf16x8 av[4], bv[4];
    #pragma unroll
    for (int t = 0; t < 4; ++t) {
      av[t] = *(const bf16x8*)(sAr + t * 1024);
      bv[t] = *(const bf16x8*)(sBr + t * 1024);
    }
    #pragma unroll
    for (int tm = 0; tm < 4; ++tm)
      #pragma unroll
      for (int tn = 0; tn < 4; ++tn)
        acc[tm][tn] = __builtin_amdgcn_mfma_f32_16x16x32_bf16(av[tm], bv[tn], acc[tm][tn], 0, 0, 0);
    __syncthreads();
  }

  // C/D layout: col = lane&15, row = (lane>>4)*4 + reg
  const int cm = (lane >> 4) * 4;
  const int cn = lane & 15;
  #pragma unroll
  for (int tm = 0; tm < 4; ++tm)
    #pragma unroll
    for (int tn = 0; tn < 4; ++tn) {
      float* cp = C + (size_t)(m0 + wm + tm * 16 + cm) * Nd + (n0 + wn + tn * 16 + cn);
      #pragma unroll
      for (int r = 0; r < 4; ++r) cp[(size_t)r * Nd] = acc[tm][tn][r];
    }
}

extern "C" void kernel_launch(void* const* d_in, const int* in_sizes, int n_in,
                              void* d_out, int out_size, void* d_ws, size_t ws_size,
                              hipStream_t stream) {
  const float* X = (const float*)d_in[0];
  const float* A = (const float*)d_in[1];
  const float* p = (const float*)d_in[2];
  float* out0 = (float*)d_out;                      // X_pooled 4096x256
  float* out1 = out0 + (size_t)K_SEL * F_DIM;       // A_pooled 4096x4096

  // ws layout: y (32KB) | rank (32KB) | Abf (64MB) | Bt (64MB)  == round-1 total
  char* ws = (char*)d_ws;
  float* y = (float*)ws;
  int* rank = (int*)(ws + 32768);
  unsigned short* Abf = (unsigned short*)(ws + 65536);
  unsigned short* Bt = (unsigned short*)(ws + 65536 + (size_t)K_SEL * N_NODES * 2);

  compute_y<<<N_NODES / 4, 256, 0, stream>>>(X, p, y);
  topk_radix<<<1, 1024, 0, stream>>>(y, rank);
  x_pool<<<N_NODES, 256, 0, stream>>>(X, y, rank, out0);
  gather_both<<<dim3(N_NODES / 64, N_NODES / 64), 256, 0, stream>>>(A, rank, Abf, Bt);
  gemm_bt<<<dim3(K_SEL / BM, K_SEL / BN), 256, 0, stream>>>(Abf, Bt, out1);
}

// Round 3
// 588.205 us; speedup vs baseline: 1.6919x; 1.3889x over previous
//
#include <hip/hip_runtime.h>
#include <hip/hip_bf16.h>

// TopKPool: N=8192 nodes, F=256 features, k=4096 kept.
// out = [X_pooled (4096x256 f32) | A_pooled (4096x4096 f32)]
// A_pooled = A[idx,:] @ A[:,idx] (0.275 TFLOP) instead of (A@A)[idx][:,idx].
// Round 3: fp8 e4m3 operands (A in [0,1) fits directly, scale=1.0) through
// mfma_scale_f32_16x16x128_f8f6f4 at 2x bf16 rate; fp8 gather (half traffic);
// 16B-subchunk XOR-swizzled LDS (b128-floor, conflict-free).

#define N_NODES 8192
#define F_DIM   256
#define K_SEL   4096

typedef float floatx4 __attribute__((ext_vector_type(4)));
typedef int   intx4   __attribute__((ext_vector_type(4)));
typedef int   intx8   __attribute__((ext_vector_type(8)));

__device__ __forceinline__ void async_copy16(const void* g, void* l) {
  __builtin_amdgcn_global_load_lds((const __attribute__((address_space(1))) void*)g,
                                   (__attribute__((address_space(3))) void*)l,
                                   16, 0, 0);
}

// ---------------- y = X @ (p / ||p||) : one wave per row ----------------
__global__ __launch_bounds__(256) void compute_y(const float* __restrict__ X,
                                                 const float* __restrict__ p,
                                                 float* __restrict__ y) {
  __shared__ __align__(16) float s_p[F_DIM];
  __shared__ float s_part[4];
  __shared__ float s_inv;
  const int tid = threadIdx.x;
  float pv = p[tid];
  s_p[tid] = pv;
  float sq = pv * pv;
  #pragma unroll
  for (int off = 32; off > 0; off >>= 1) sq += __shfl_down(sq, off, 64);
  if ((tid & 63) == 0) s_part[tid >> 6] = sq;
  __syncthreads();
  if (tid == 0) s_inv = rsqrtf(s_part[0] + s_part[1] + s_part[2] + s_part[3]);
  __syncthreads();
  const int wave = tid >> 6, lane = tid & 63;
  const int row = blockIdx.x * 4 + wave;
  const float4* xr = (const float4*)(X + (size_t)row * F_DIM);
  const float4* pr = (const float4*)s_p;
  float4 xv = xr[lane];
  float4 pw = pr[lane];
  float d = xv.x * pw.x + xv.y * pw.y + xv.z * pw.z + xv.w * pw.w;
  #pragma unroll
  for (int off = 32; off > 0; off >>= 1) d += __shfl_down(d, off, 64);
  if (lane == 0) y[row] = d * s_inv;
}

// ---------------- exact top-k via binary-search select ----------------
// rank[i] = position among kept nodes in ascending-index order, or -1.
// Ties at threshold keep lowest indices (matches top_k stability + sort).
__device__ __forceinline__ unsigned block_exscan(unsigned tv, unsigned* scan, int tid) {
  scan[tid] = tv;
  __syncthreads();
  for (int o = 1; o < 1024; o <<= 1) {
    unsigned add = (tid >= o) ? scan[tid - o] : 0u;
    __syncthreads();
    scan[tid] += add;
    __syncthreads();
  }
  unsigned incl = scan[tid];
  __syncthreads();
  return incl - tv;
}

__global__ __launch_bounds__(1024) void topk_radix(const float* __restrict__ y,
                                                   int* __restrict__ rank) {
  __shared__ unsigned keys[N_NODES];   // 32 KB
  __shared__ unsigned scan[1024];      // 4 KB
  __shared__ unsigned s_cnt;
  const int tid = threadIdx.x;
  for (int i = tid; i < N_NODES; i += 1024) {
    unsigned u = __float_as_uint(y[i]);
    keys[i] = (u & 0x80000000u) ? ~u : (u | 0x80000000u);  // monotone map
  }
  __syncthreads();
  const int base = tid << 3;
  unsigned lo = 0u, hi = 0xFFFFFFFFu;
  while (lo < hi) {
    unsigned mid = lo + ((hi - lo) >> 1) + 1u;
    if (tid == 0) s_cnt = 0;
    __syncthreads();
    unsigned c = 0;
    #pragma unroll
    for (int j = 0; j < 8; ++j) c += (keys[base + j] >= mid) ? 1u : 0u;
    #pragma unroll
    for (int o = 32; o > 0; o >>= 1) c += __shfl_down(c, o, 64);
    if ((tid & 63) == 0) atomicAdd(&s_cnt, c);
    __syncthreads();
    unsigned tot = s_cnt;
    if (tot >= K_SEL) lo = mid; else hi = mid - 1u;
    __syncthreads();
  }
  const unsigned T = lo;
  if (tid == 0) s_cnt = 0;
  __syncthreads();
  {
    unsigned c = 0;
    #pragma unroll
    for (int j = 0; j < 8; ++j) c += (keys[base + j] > T) ? 1u : 0u;
    #pragma unroll
    for (int o = 32; o > 0; o >>= 1) c += __shfl_down(c, o, 64);
    if ((tid & 63) == 0) atomicAdd(&s_cnt, c);
  }
  __syncthreads();
  const unsigned need_eq = (unsigned)K_SEL - s_cnt;
  __syncthreads();
  unsigned e[8], g[8], te = 0;
  #pragma unroll
  for (int j = 0; j < 8; ++j) {
    unsigned k = keys[base + j];
    e[j] = (k == T) ? 1u : 0u;
    g[j] = (k > T) ? 1u : 0u;
    te += e[j];
  }
  unsigned eqr = block_exscan(te, scan, tid);
  unsigned keep[8], tk = 0;
  #pragma unroll
  for (int j = 0; j < 8; ++j) {
    unsigned kp = g[j] | (e[j] & ((eqr < need_eq) ? 1u : 0u));
    eqr += e[j];
    keep[j] = kp;
    tk += kp;
  }
  unsigned pos = block_exscan(tk, scan, tid);
  #pragma unroll
  for (int j = 0; j < 8; ++j) {
    if (keep[j]) { rank[base + j] = (int)pos; pos++; }
    else rank[base + j] = -1;
  }
}

// ---------------- fused gather -> fp8: one pass over A ----------------
// Abf8[rank[r], c] = e4m3(A[r, c])   (selected rows, K contiguous)
// Bt8 [rank[c], r] = e4m3(A[r, c])   (selected cols, transposed)
__global__ __launch_bounds__(256) void gather_both(const float* __restrict__ A,
                                                   const int* __restrict__ rank,
                                                   unsigned char* __restrict__ Abf8,
                                                   unsigned char* __restrict__ Bt8) {
  __shared__ float tile[64][65];
  __shared__ int rr_[64], rc_[64];
  const int tid = threadIdx.x;
  const int r0 = blockIdx.y << 6, c0 = blockIdx.x << 6;
  if (tid < 64) rr_[tid] = rank[r0 + tid];
  else if (tid < 128) rc_[tid - 64] = rank[c0 + tid - 64];
  const int trow = tid >> 4, tc4 = (tid & 15) << 2;
  #pragma unroll
  for (int i = 0; i < 4; ++i) {
    const float4 v = *(const float4*)(A + (size_t)(r0 + trow + i * 16) * N_NODES + c0 + tc4);
    tile[trow + i * 16][tc4 + 0] = v.x;
    tile[trow + i * 16][tc4 + 1] = v.y;
    tile[trow + i * 16][tc4 + 2] = v.z;
    tile[trow + i * 16][tc4 + 3] = v.w;
  }
  __syncthreads();
  const int wv = tid >> 6, ln = tid & 63;
  const int sub = ln >> 4, m4 = (ln & 15) << 2;
  // rows -> Abf8 (4B packed stores)
  #pragma unroll
  for (int t = 0; t < 4; ++t) {
    int row = (wv << 4) + (t << 2) + sub;
    int rk = rr_[row];
    if (rk >= 0) {
      int v = __builtin_amdgcn_cvt_pk_fp8_f32(tile[row][m4 + 0], tile[row][m4 + 1], 0, false);
      v = __builtin_amdgcn_cvt_pk_fp8_f32(tile[row][m4 + 2], tile[row][m4 + 3], v, true);
      *(int*)(Abf8 + (size_t)rk * N_NODES + c0 + m4) = v;
    }
  }
  // cols -> Bt8 (transposed, 4B packed stores)
  #pragma unroll
  for (int t = 0; t < 4; ++t) {
    int col = (wv << 4) + (t << 2) + sub;
    int rk = rc_[col];
    if (rk >= 0) {
      int v = __builtin_amdgcn_cvt_pk_fp8_f32(tile[m4 + 0][col], tile[m4 + 1][col], 0, false);
      v = __builtin_amdgcn_cvt_pk_fp8_f32(tile[m4 + 2][col], tile[m4 + 3][col], v, true);
      *(int*)(Bt8 + (size_t)rk * N_NODES + r0 + m4) = v;
    }
  }
}

// ---------------- X_pooled[rank[i],:] = X[i,:] * tanh(y[i]) ----------------
__global__ __launch_bounds__(256) void x_pool(const float* __restrict__ X,
                                              const float* __restrict__ y,
                                              const int* __restrict__ rank,
                                              float* __restrict__ out0) {
  const int i = blockIdx.x;
  const int r = rank[i];
  if (r < 0) return;
  const float g = tanhf(y[i]);
  out0[(size_t)r * F_DIM + threadIdx.x] = X[(size_t)i * F_DIM + threadIdx.x] * g;
}

// ---------------- C[m,n] = sum_k A8[m,k] * B8[n,k] (fp8 MX, scale=1.0) ----------------
// LDS layout: row r (128 B) split into 8 16-B subchunks; global subchunk s
// stored at slot r*8 + (s ^ (r&7)). Staging stays lane-contiguous for
// global_load_lds; ds_read_b128 spreads 8 lanes/bank-quad (the b128 floor).
#define BM  128
#define BN  128
#define BKB 128  // K elements (=bytes) per tile

__global__ __launch_bounds__(256) void gemm_fp8(const unsigned char* __restrict__ A,
                                                const unsigned char* __restrict__ B,
                                                float* __restrict__ C) {
  const int Kd = N_NODES;  // 8192
  const int Nd = K_SEL;    // 4096
  __shared__ unsigned char sA[BM * BKB];  // 16 KB
  __shared__ unsigned char sB[BN * BKB];  // 16 KB
  const int tid = threadIdx.x;
  const int wave = tid >> 6, lane = tid & 63;
  const int m0 = blockIdx.x * BM, n0 = blockIdx.y * BN;
  const int wm = (wave >> 1) * 64, wn = (wave & 1) * 64;

  // staging: copy i handles 16B slot S = i*256 + tid
  const unsigned char* Ag[4];
  const unsigned char* Bg[4];
  char* lA[4];
  char* lB[4];
  #pragma unroll
  for (int i = 0; i < 4; ++i) {
    int S = i * 256 + tid;
    int r = S >> 3;
    int sg = (S & 7) ^ (r & 7);
    Ag[i] = A + (size_t)(m0 + r) * Kd + sg * 16;
    Bg[i] = B + (size_t)(n0 + r) * Kd + sg * 16;
    lA[i] = (char*)sA + i * 4096 + wave * 1024;
    lB[i] = (char*)sB + i * 4096 + wave * 1024;
  }

  floatx4 acc[4][4] = {};

  const int l15 = lane & 15, q = lane >> 4;
  // A-frag (16x16x128): row = lane&15, k = q*32 + j (32 consecutive bytes)
  int offAlo[4], offAhi[4], offBlo[4], offBhi[4];
  #pragma unroll
  for (int t = 0; t < 4; ++t) {
    int RA = wm + t * 16 + l15;
    int RB = wn + t * 16 + l15;
    offAlo[t] = RA * 128 + (((2 * q) ^ (RA & 7)) << 4);
    offAhi[t] = RA * 128 + (((2 * q + 1) ^ (RA & 7)) << 4);
    offBlo[t] = RB * 128 + (((2 * q) ^ (RB & 7)) << 4);
    offBhi[t] = RB * 128 + (((2 * q + 1) ^ (RB & 7)) << 4);
  }

  for (int kt = 0; kt < Kd; kt += BKB) {
    #pragma unroll
    for (int i = 0; i < 4; ++i) {
      async_copy16(Ag[i] + kt, lA[i]);
      async_copy16(Bg[i] + kt, lB[i]);
    }
    __syncthreads();
    intx8 av[4], bv[4];
    #pragma unroll
    for (int t = 0; t < 4; ++t) {
      intx4 lo = *(const intx4*)((const char*)sA + offAlo[t]);
      intx4 hi = *(const intx4*)((const char*)sA + offAhi[t]);
      av[t] = __builtin_shufflevector(lo, hi, 0, 1, 2, 3, 4, 5, 6, 7);
      lo = *(const intx4*)((const char*)sB + offBlo[t]);
      hi = *(const intx4*)((const char*)sB + offBhi[t]);
      bv[t] = __builtin_shufflevector(lo, hi, 0, 1, 2, 3, 4, 5, 6, 7);
    }
    #pragma unroll
    for (int tm = 0; tm < 4; ++tm)
      #pragma unroll
      for (int tn = 0; tn < 4; ++tn)
        acc[tm][tn] = __builtin_amdgcn_mfma_scale_f32_16x16x128_f8f6f4(
            av[tm], bv[tn], acc[tm][tn],
            0, 0,                    // cbsz=fp8(e4m3), blgp=fp8(e4m3)
            0, 0x7F7F7F7F,           // scale_a opsel, scale_a = 1.0 (e8m0 127)
            0, 0x7F7F7F7F);          // scale_b opsel, scale_b = 1.0
    __syncthreads();
  }

  // C/D layout (shape-determined): col = lane&15, row = (lane>>4)*4 + reg
  const int cm = (lane >> 4) * 4;
  const int cn = lane & 15;
  #pragma unroll
  for (int tm = 0; tm < 4; ++tm)
    #pragma unroll
    for (int tn = 0; tn < 4; ++tn) {
      float* cp = C + (size_t)(m0 + wm + tm * 16 + cm) * Nd + (n0 + wn + tn * 16 + cn);
      #pragma unroll
      for (int r = 0; r < 4; ++r) cp[(size_t)r * Nd] = acc[tm][tn][r];
    }
}

extern "C" void kernel_launch(void* const* d_in, const int* in_sizes, int n_in,
                              void* d_out, int out_size, void* d_ws, size_t ws_size,
                              hipStream_t stream) {
  const float* X = (const float*)d_in[0];
  const float* A = (const float*)d_in[1];
  const float* p = (const float*)d_in[2];
  float* out0 = (float*)d_out;                      // X_pooled 4096x256
  float* out1 = out0 + (size_t)K_SEL * F_DIM;       // A_pooled 4096x4096

  // ws layout: y (32KB) | rank (32KB) | Abf8 (32MB) | Bt8 (32MB)
  char* ws = (char*)d_ws;
  float* y = (float*)ws;
  int* rank = (int*)(ws + 32768);
  unsigned char* Abf8 = (unsigned char*)(ws + 65536);
  unsigned char* Bt8 = Abf8 + (size_t)K_SEL * N_NODES;

  compute_y<<<N_NODES / 4, 256, 0, stream>>>(X, p, y);
  topk_radix<<<1, 1024, 0, stream>>>(y, rank);
  x_pool<<<N_NODES, 256, 0, stream>>>(X, y, rank, out0);
  gather_both<<<dim3(N_NODES / 64, N_NODES / 64), 256, 0, stream>>>(A, rank, Abf8, Bt8);
  gemm_fp8<<<dim3(K_SEL / BM, K_SEL / BN), 256, 0, stream>>>(Abf8, Bt8, out1);
}